// Round 13
// baseline (65.668 us; speedup 1.0000x reference)
//
#include <hip/hip_runtime.h>
#include <hip/hip_fp16.h>

#define D_  160
#define H_  192
#define W_  224
#define HW_ (H_ * W_)           // 43008
#define HW2_ (HW_ / 2)          // 21504
#define N_  (D_ * H_ * W_)      // 6881280
#define INV729 (1.0f / 729.0f)
#define HSEG 12
#define NSEG (H_ / HSEG)        // 16
#define NROW (HSEG + 9)         // 21 rows pushed per strip
#define UPD  (NSEG * 2)         // wave-units per d = 32
#define RING 8                  // LDS row-buffer ring (1024 B each)

// Intermediate: bufA = uint4 per 2 points (c0..c3 pt0, c0..c3 pt1, fp16)
//               bufB = dword per 2 points (c4 pt0, c4 pt1, fp16)

typedef __attribute__((address_space(1))) const unsigned GU;
typedef __attribute__((address_space(3))) unsigned LU;

__device__ __forceinline__ unsigned pack2(float a, float b) {
    const __half2 h = __floats2half2_rn(a, b);
    return *(const unsigned*)&h;
}

// Counted vmcnt wait for step p (compile-time p after full unroll).
// Exact younger-op counts: p<=9:5, 10:7, 11:9, 12:11, 13:13, >=14:15
// (1 load/step always; +2 stores/step from p>=9). Margin -3 for intra-step
// reordering of {stores, load-issue} around the boundary step. Never 0.
__device__ __forceinline__ void vmwait_step(int p) {
    if (p <= 9)       asm volatile("s_waitcnt vmcnt(2)"  ::: "memory");
    else if (p == 10) asm volatile("s_waitcnt vmcnt(4)"  ::: "memory");
    else if (p == 11) asm volatile("s_waitcnt vmcnt(6)"  ::: "memory");
    else if (p == 12) asm volatile("s_waitcnt vmcnt(8)"  ::: "memory");
    else if (p == 13) asm volatile("s_waitcnt vmcnt(10)" ::: "memory");
    else              asm volatile("s_waitcnt vmcnt(12)" ::: "memory");
    __builtin_amdgcn_sched_barrier(0);
}

// ---------------------------------------------------------------------------
__global__ void k_init(double* acc, float* zpage) {
    if (threadIdx.x == 0) *acc = 0.0;
    if (threadIdx.x < 16) zpage[threadIdx.x] = 0.f;
}

// ---------------------------------------------------------------------------
// Fused W+H box-sum — wave-autonomous, global_load_lds staging (no ds_write),
// 8-buffer LDS ring, 6 loads in flight, counted vmcnt (T4).
// Row buffer layout (1024 B): floats 0..119 = I(w-4..115 rel), 120..239 = J,
// 240..255 = junk (lanes 60-63). One load instr per row: lane i writes 16 B
// at lds_base + i*16; per-lane global addr selects I/J/zeros-page.
__global__ __launch_bounds__(256) void k_passWH(const float* __restrict__ pred,
                                                const float* __restrict__ targ,
                                                uint4* __restrict__ outA,      // [N/2]
                                                unsigned* __restrict__ outB,   // [N/2]
                                                const float* __restrict__ zpage) {
    __shared__ __attribute__((aligned(16))) float lds[4][RING][256];
    const int wid  = threadIdx.x >> 6;
    const int lane = threadIdx.x & 63;
    const int unit = blockIdx.x * 4 + wid;
    const int d    = unit / UPD;
    const int rem  = unit % UPD;
    const int half = rem & 1;
    const int h0   = (rem >> 1) * HSEG;
    const long dbase = (long)d * HW_;
    const int wbase = half * 112;            // first output w of this half

    // load-lane role: lanes 0-29 I(targ) chunks, 30-59 J(pred), 60-63 junk.
    const int  jj  = (lane < 30) ? lane : lane - 30;   // chunk 0..29
    const int  ws  = wbase - 4 + 4 * jj;               // chunk w-start
    const bool chunk_ok = (lane < 60) && (ws >= 0) && (ws + 3 < W_);
    const float* csrc = ((lane < 30) ? targ : pred) + dbase + ws; // only deref'd if chunk_ok

    // fp32 H-ring
    float2 q[5][9];
    #pragma unroll
    for (int c = 0; c < 5; ++c)
        #pragma unroll
        for (int k = 0; k < 9; ++k) q[c][k] = make_float2(0.f, 0.f);
    float S0[5] = {0,0,0,0,0}, S1[5] = {0,0,0,0,0};

    // issue async load of push-row r into ring slot r%8 (r compile-time)
    auto issue = [&](int r) {
        const int hh = h0 - 5 + r;
        const bool rok = (hh >= 0) && (hh < H_);
        const float* ga = (chunk_ok && rok) ? (csrc + (long)hh * W_) : zpage;
        __builtin_amdgcn_global_load_lds((GU*)ga, (LU*)&lds[wid][r & 7][0], 16, 0, 0);
    };

    // prologue: 6 loads in flight
    issue(0); issue(1); issue(2); issue(3); issue(4); issue(5);

    #pragma unroll
    for (int p = 0; p < NROW; ++p) {
        vmwait_step(p);                      // row p resident in slot p%8

        if (lane < 56) {                     // compute lane owns w0 = wbase+2*lane
            const float* buf = &lds[wid][p & 7][0];
            float a[10], b[10];
            #pragma unroll
            for (int m = 0; m < 5; ++m) {
                const float2 va = *(const float2*)&buf[2 * lane + 2 * m];
                const float2 vb = *(const float2*)&buf[120 + 2 * lane + 2 * m];
                a[2*m] = va.x; a[2*m+1] = va.y;
                b[2*m] = vb.x; b[2*m+1] = vb.y;
            }
            float sI = 0.f, sJ = 0.f, sII = 0.f, sJJ = 0.f, sIJ = 0.f;
            #pragma unroll
            for (int kk = 0; kk < 9; ++kk) {
                sI  += a[kk];          sJ  += b[kk];
                sII += a[kk] * a[kk];  sJJ += b[kk] * b[kk];
                sIJ += a[kk] * b[kk];
            }
            float w0[5], w1[5];
            w0[0] = sI;  w1[0] = sI  + a[9] - a[0];
            w0[1] = sJ;  w1[1] = sJ  + b[9] - b[0];
            w0[2] = sII; w1[2] = sII + a[9]*a[9] - a[0]*a[0];
            w0[3] = sJJ; w1[3] = sJJ + b[9]*b[9] - b[0]*b[0];
            w0[4] = sIJ; w1[4] = sIJ + a[9]*b[9] - a[0]*b[0];

            const int ph = p % 9;            // compile-time (full unroll)
            #pragma unroll
            for (int c = 0; c < 5; ++c) {
                S0[c] += w0[c] - q[c][ph].x;
                S1[c] += w1[c] - q[c][ph].y;
                q[c][ph].x = w0[c];
                q[c][ph].y = w1[c];
            }
            if (p >= 9) {                    // emit row h0+p-9 (2 vmcnt stores)
                const long rb = dbase + (long)(h0 + p - 9) * W_;  // even
                uint4 oA;
                oA.x = pack2(S0[0], S0[1]); oA.y = pack2(S0[2], S0[3]);
                oA.z = pack2(S1[0], S1[1]); oA.w = pack2(S1[2], S1[3]);
                outA[rb / 2 + half * 56 + lane] = oA;
                outB[rb / 2 + half * 56 + lane] = pack2(S0[4], S1[4]);
            }
        }
        // refill: keep 6 loads in flight; slot (p+6)%8 held row p-2 (consumed).
        // Rows beyond NROW-1 load junk (clamped addressing) to keep the
        // vmcnt cadence exactly 1 load/step.
        issue(p + 6);
        __builtin_amdgcn_sched_barrier(0);   // pin step boundary
    }
}

// ---------------------------------------------------------------------------
// D-axis 9-tap sliding sum + cc + reduction. TWO points per thread: one b128
// (bufA) + one b32 (bufB) per d-step. (unchanged — proven ~10 us)
__global__ __launch_bounds__(256) void k_passD(const uint4* __restrict__ bufA,
                                               const unsigned* __restrict__ bufB,
                                               double* __restrict__ acc) {
    const int DSEG = D_ / 8;                // 20
    const int p2 = blockIdx.x * blockDim.x + threadIdx.x;   // < HW2_
    const int d0 = blockIdx.y * DSEG;

    float2 q[5][9], S[5];                   // .x = pt0, .y = pt1
    #pragma unroll
    for (int c = 0; c < 5; ++c) S[c] = make_float2(0.f, 0.f);

    #pragma unroll
    for (int k = 0; k < 9; ++k) {
        const int dd = d0 - 5 + k;          // d0+3 <= 143 < 160
        uint4 va = make_uint4(0u, 0u, 0u, 0u);
        unsigned vb = 0u;
        if (dd >= 0) {
            va = bufA[(long)dd * HW2_ + p2];
            vb = bufB[(long)dd * HW2_ + p2];
        }
        const float2 a01 = __half22float2(*(const __half2*)&va.x);
        const float2 a23 = __half22float2(*(const __half2*)&va.y);
        const float2 b01 = __half22float2(*(const __half2*)&va.z);
        const float2 b23 = __half22float2(*(const __half2*)&va.w);
        const float2 c44 = __half22float2(*(const __half2*)&vb);
        q[0][k] = make_float2(a01.x, b01.x); S[0].x += a01.x; S[0].y += b01.x;
        q[1][k] = make_float2(a01.y, b01.y); S[1].x += a01.y; S[1].y += b01.y;
        q[2][k] = make_float2(a23.x, b23.x); S[2].x += a23.x; S[2].y += b23.x;
        q[3][k] = make_float2(a23.y, b23.y); S[3].x += a23.y; S[3].y += b23.y;
        q[4][k] = make_float2(c44.x, c44.y); S[4].x += c44.x; S[4].y += c44.y;
    }

    float myacc = 0.f;
    #pragma unroll
    for (int j = 0; j < DSEG; ++j) {        // output d = d0+j
        const int dd = d0 + 4 + j;
        uint4 va = make_uint4(0u, 0u, 0u, 0u);
        unsigned vb = 0u;
        if (dd < D_) {
            va = bufA[(long)dd * HW2_ + p2];
            vb = bufB[(long)dd * HW2_ + p2];
        }
        const float2 a01 = __half22float2(*(const __half2*)&va.x);
        const float2 a23 = __half22float2(*(const __half2*)&va.y);
        const float2 b01 = __half22float2(*(const __half2*)&va.z);
        const float2 b23 = __half22float2(*(const __half2*)&va.w);
        const float2 c44 = __half22float2(*(const __half2*)&vb);
        const float2 nv[5] = {
            make_float2(a01.x, b01.x), make_float2(a01.y, b01.y),
            make_float2(a23.x, b23.x), make_float2(a23.y, b23.y),
            make_float2(c44.x, c44.y)
        };
        const int ph = j % 9;               // compile-time
        #pragma unroll
        for (int c = 0; c < 5; ++c) {
            S[c].x += nv[c].x - q[c][ph].x;
            S[c].y += nv[c].y - q[c][ph].y;
            q[c][ph] = nv[c];
        }
        #pragma unroll
        for (int e = 0; e < 2; ++e) {
            const float mu1 = (e ? S[0].y : S[0].x) * INV729;
            const float mu2 = (e ? S[1].y : S[1].x) * INV729;
            const float s1  = (e ? S[2].y : S[2].x) * INV729 - mu1 * mu1;
            const float s2  = (e ? S[3].y : S[3].x) * INV729 - mu2 * mu2;
            const float s12 = (e ? S[4].y : S[4].x) * INV729 - mu1 * mu2;
            const float den = fmaxf(s1 * s2, 1.1920929e-7f);  // finfo(f32).eps
            myacc += (s12 * s12) / den;
        }
    }

    __shared__ float red[256];
    red[threadIdx.x] = myacc;
    __syncthreads();
    #pragma unroll
    for (int s = 128; s > 0; s >>= 1) {
        if (threadIdx.x < s) red[threadIdx.x] += red[threadIdx.x + s];
        __syncthreads();
    }
    if (threadIdx.x == 0) atomicAdd(acc, (double)red[0]);
}

// ---------------------------------------------------------------------------
__global__ void k_fin(const double* __restrict__ acc, float* __restrict__ out) {
    out[0] = (float)(-(*acc) / (double)N_);
}

// ---------------------------------------------------------------------------
extern "C" void kernel_launch(void* const* d_in, const int* in_sizes, int n_in,
                              void* d_out, int out_size, void* d_ws, size_t ws_size,
                              hipStream_t stream) {
    const float* pred = (const float*)d_in[0];
    const float* targ = (const float*)d_in[1];

    const size_t offA = 0;
    const size_t offB = (size_t)(N_ / 2) * 16;                 // 55,050,240
    const size_t offAcc = offB + (size_t)(N_ / 2) * 4;         // 68,812,800
    const size_t offZ = offAcc + 64;                           // 16B-aligned

    uint4*    bufA  = (uint4*)((char*)d_ws + offA);
    unsigned* bufB  = (unsigned*)((char*)d_ws + offB);
    double*   acc   = (double*)((char*)d_ws + offAcc);
    float*    zpage = (float*)((char*)d_ws + offZ);
    float*    out   = (float*)d_out;

    k_init<<<1, 64, 0, stream>>>(acc, zpage);
    // 5120 wave-units (160 d x 16 hseg x 2 halves), 4 waves/block -> 1280 blocks
    k_passWH<<<D_ * UPD / 4, 256, 0, stream>>>(pred, targ, bufA, bufB, zpage);
    dim3 g3(HW2_ / 256, 8);     // 84 x 8 = 672 blocks
    k_passD<<<g3, 256, 0, stream>>>(bufA, bufB, acc);
    k_fin<<<1, 1, 0, stream>>>(acc, out);
}